// Round 9
// baseline (571.550 us; speedup 1.0000x reference)
//
#include <hip/hip_runtime.h>

#define KC 1024   // codes
#define DD 128    // dim
#define NT_COUNT (KC / 16)   // 64 code-tiles of 16
#define RPB 64    // rows per block (one wave, 4 m-tiles)

typedef short bf16x8 __attribute__((ext_vector_type(8)));
typedef float f32x4  __attribute__((ext_vector_type(4)));
typedef unsigned long long u64;

#define AS1 __attribute__((address_space(1)))
#define AS3 __attribute__((address_space(3)))

static __device__ __forceinline__ unsigned short f2bf(float f) {
    unsigned u = __float_as_uint(f);
    unsigned r = (u + 0x7fffu + ((u >> 16) & 1u)) >> 16;   // RNE
    return (unsigned short)r;
}
static __device__ __forceinline__ float bf2f(unsigned short h) {
    return __uint_as_float(((unsigned)h) << 16);
}
static __device__ __forceinline__ void gl_lds16(const void* g, void* l) {
    __builtin_amdgcn_global_load_lds((const AS1 void*)g, (AS3 void*)l, 16, 0, 0);
}
static __device__ __forceinline__ void gl_lds4(const void* g, void* l) {
    __builtin_amdgcn_global_load_lds((const AS1 void*)g, (AS3 void*)l, 4, 0, 0);
}

// ---------------- fused prep ----------------
// e2h = 512 - 0.5||e_k||^2 ; ET = E^T (fp32 exact) ; Bpk = bf16 HI-ONLY B-frags
//   Bpk byte layout: [nt][c(4)x1024][lane(64)x16]; element (d,k):
//   d = c*32 + (lane>>4)*8 + j ; k = nt*16 + (lane&15)
// gtab[nt] = max_k ||e_k - bf16(e_k)||^2 over this tile; gtab[64+nt] = max ||e_k||^2
__global__ __launch_bounds__(256) void vq_prep(const float* __restrict__ E,
                                               float* __restrict__ e2h,
                                               float* __restrict__ gtab,
                                               float* __restrict__ ET,
                                               unsigned short* __restrict__ Bpk) {
    __shared__ float T[16 * 129];   // [k][d]
    __shared__ float red[32];
    const int nt  = blockIdx.x;     // 64 blocks, 16 codes each
    const int tid = threadIdx.x;

    for (int i = tid; i < 16 * DD; i += 256) {
        int d  = i >> 4;
        int kk = i & 15;
        T[kk * 129 + d] = E[(size_t)d * KC + nt * 16 + kk];
    }
    __syncthreads();

    if (tid < 16) {
        float s = 0.f, g = 0.f;
#pragma unroll 16
        for (int d = 0; d < DD; ++d) {
            float v = T[tid * 129 + d];
            s = fmaf(v, v, s);
            float lo = v - bf2f(f2bf(v));
            g = fmaf(lo, lo, g);
        }
        e2h[nt * 16 + tid] = 512.0f - 0.5f * s;
        red[tid] = g;
        red[16 + tid] = s;
    }
    __syncthreads();
    if (tid == 0) {
        float mg = 0.f, ms = 0.f;
#pragma unroll
        for (int i = 0; i < 16; ++i) { mg = fmaxf(mg, red[i]); ms = fmaxf(ms, red[16 + i]); }
        gtab[nt] = mg;
        gtab[64 + nt] = ms;
    }

    for (int i = tid; i < 16 * DD; i += 256) {
        int kk = i >> 7;
        int d  = i & 127;
        ET[(size_t)(nt * 16 + kk) * DD + d] = T[kk * 129 + d];
    }

    {   // hi-only pack: 4 chunks x 64 lanes = 256 threads
        const int c    = tid >> 6;
        const int lane = tid & 63;
        const int kk   = lane & 15;
        const int d0   = c * 32 + (lane >> 4) * 8;
        bf16x8 hi;
#pragma unroll
        for (int j = 0; j < 8; ++j) hi[j] = (short)f2bf(T[kk * 129 + d0 + j]);
        *(bf16x8*)((char*)Bpk + (size_t)nt * 4096 + c * 1024 + lane * 16) = hi;
    }
}

// ---------------- main: single-wave, 64 rows, 2-PASS screen (B = hi limb only) ----------------
// Screen err per row is CERTIFIED: E_row = xn*(max||e_lo|| + 2^-17*1.05*max||e||) + 0.008
// (missing x*e_lo + A double-round + fp32 accum + e2h + 6-bit mask). Top-4 tracked in-loop;
// per row: depth = first j with gap(j,j+1) >= 2E -> fp64 rescore top-j; none -> fp64 FULL scan.
__global__ __launch_bounds__(64, 2) void vq_main(const float* __restrict__ X,
                                                 const float* __restrict__ e2h,
                                                 const float* __restrict__ gtab,
                                                 const float* __restrict__ ET,
                                                 const unsigned short* __restrict__ Bpk,
                                                 float* __restrict__ Out) {
    __shared__ __align__(16) char lds[11008];
    // [0,8704): two stage buffers (4096 B-frags + 256 e2 each); dump area post-loop (8 KB)
    float* s_xn   = (float*)(lds + 8704);   // [64] ||x_row||^2
    int*   s_cand = (int*)(lds + 8960);     // [64][4]
    int*   s_dep  = (int*)(lds + 9984);     // [64] rescue depth (0 = full scan)
    int*   s_win  = (int*)(lds + 10240);    // [64]
    int*   s_nfs  = (int*)(lds + 10496);
    int*   s_fsl  = (int*)(lds + 10500);    // [64]

    const int lane  = threadIdx.x;   // single wave
    const int quad  = lane >> 4;
    const int n16   = lane & 15;
    const int wrow0 = blockIdx.x * RPB;
    const int lidx16 = lane * 16;
    const int lidx4  = lane * 4;

    // ---- error-bound coefficient from prep tables (wave-wide max reduce)
    float g1 = gtab[lane];        // max ||e_lo||^2 per tile
    float g2 = gtab[64 + lane];   // max ||e||^2 per tile
#pragma unroll
    for (int m = 1; m < 64; m <<= 1) {
        g1 = fmaxf(g1, __shfl_xor(g1, m, 64));
        g2 = fmaxf(g2, __shfl_xor(g2, m, 64));
    }
    const float Ecoef = sqrtf(g1) * 1.001f + 8.2e-6f * sqrtf(g2);

    // ---- A-fragments (hi+lo limbs, 128 VGPRs) + row-norm partials
    bf16x8 ahi[4][4], alo[4][4];
    float psum[4] = {0.f, 0.f, 0.f, 0.f};
#pragma unroll
    for (int t = 0; t < 4; ++t) {
#pragma unroll
        for (int s = 0; s < 4; ++s) {
            const int row = wrow0 + t * 16 + n16;
            const int d0  = s * 32 + quad * 8;
            const float4 p = *(const float4*)(X + (size_t)row * DD + d0);
            const float4 q = *(const float4*)(X + (size_t)row * DD + d0 + 4);
            float v[8] = {p.x, p.y, p.z, p.w, q.x, q.y, q.z, q.w};
#pragma unroll
            for (int j = 0; j < 8; ++j) {
                psum[t] = fmaf(v[j], v[j], psum[t]);
                unsigned short h = f2bf(v[j]);
                ahi[t][s][j] = (short)h;
                alo[t][s][j] = (short)f2bf(v[j] - bf2f(h));
            }
        }
    }
#pragma unroll
    for (int t = 0; t < 4; ++t) {   // quad-reduce: full ||x_row||^2 on every lane
        psum[t] += __shfl_xor(psum[t], 16, 64);
        psum[t] += __shfl_xor(psum[t], 32, 64);
    }
    if (quad == 0)
#pragma unroll
        for (int t = 0; t < 4; ++t) s_xn[t * 16 + n16] = psum[t];
    if (lane == 0) *s_nfs = 0;

    // ---- top-4 trackers: positive floats with 6-bit tile id in low mantissa bits
    float p1[4][4], p2[4][4], p3[4][4], p4[4][4];
#pragma unroll
    for (int t = 0; t < 4; ++t)
#pragma unroll
        for (int r = 0; r < 4; ++r) { p1[t][r] = 0.f; p2[t][r] = 0.f; p3[t][r] = 0.f; p4[t][r] = 0.f; }

#define STAGE(NT, BOFF)                                                          \
    do {                                                                         \
        const char* g = (const char*)Bpk + (size_t)(NT) * 4096;                  \
        _Pragma("unroll")                                                        \
        for (int c = 0; c < 4; ++c)                                              \
            gl_lds16(g + c * 1024 + lidx16, lds + (BOFF) + c * 1024);            \
        gl_lds4(e2h + (NT) * 16 + n16, lds + (BOFF) + 4096);                     \
    } while (0)

#define TILE(NT, BOFF)                                                           \
    do {                                                                         \
        const char* l = lds + (BOFF);                                            \
        const bf16x8 bh0 = *(const bf16x8*)(l + 0 * 1024 + lidx16);              \
        const bf16x8 bh1 = *(const bf16x8*)(l + 1 * 1024 + lidx16);              \
        const bf16x8 bh2 = *(const bf16x8*)(l + 2 * 1024 + lidx16);              \
        const bf16x8 bh3 = *(const bf16x8*)(l + 3 * 1024 + lidx16);              \
        const float  ev  = *(const float*)(l + 4096 + lidx4);                    \
        const unsigned ntinv = (unsigned)(63 - (NT));                            \
        _Pragma("unroll")                                                        \
        for (int t = 0; t < 4; ++t) {                                            \
            f32x4 aA = {ev, ev, ev, ev};                                         \
            f32x4 aB = {0.f, 0.f, 0.f, 0.f};                                     \
            aA = __builtin_amdgcn_mfma_f32_16x16x32_bf16(ahi[t][0], bh0, aA, 0, 0, 0); \
            aB = __builtin_amdgcn_mfma_f32_16x16x32_bf16(alo[t][0], bh0, aB, 0, 0, 0); \
            aA = __builtin_amdgcn_mfma_f32_16x16x32_bf16(ahi[t][1], bh1, aA, 0, 0, 0); \
            aB = __builtin_amdgcn_mfma_f32_16x16x32_bf16(alo[t][1], bh1, aB, 0, 0, 0); \
            aA = __builtin_amdgcn_mfma_f32_16x16x32_bf16(ahi[t][2], bh2, aA, 0, 0, 0); \
            aB = __builtin_amdgcn_mfma_f32_16x16x32_bf16(alo[t][2], bh2, aB, 0, 0, 0); \
            aA = __builtin_amdgcn_mfma_f32_16x16x32_bf16(ahi[t][3], bh3, aA, 0, 0, 0); \
            aB = __builtin_amdgcn_mfma_f32_16x16x32_bf16(alo[t][3], bh3, aB, 0, 0, 0); \
            _Pragma("unroll")                                                    \
            for (int r = 0; r < 4; ++r) {                                        \
                float sv = aA[r] + aB[r];                                        \
                float v = __uint_as_float((__float_as_uint(sv) & ~63u) | ntinv); \
                float t1 = fmaxf(p1[t][r], v), b1 = fminf(p1[t][r], v);          \
                float t2 = fmaxf(p2[t][r], b1), b2 = fminf(p2[t][r], b1);        \
                float t3 = fmaxf(p3[t][r], b2), b3 = fminf(p3[t][r], b2);        \
                p4[t][r] = fmaxf(p4[t][r], b3);                                  \
                p1[t][r] = t1; p2[t][r] = t2; p3[t][r] = t3;                     \
            }                                                                    \
        }                                                                        \
    } while (0)

    STAGE(0, 0);
    for (int nt = 0; nt < NT_COUNT; nt += 2) {
        STAGE(nt + 1, 4352);
        __builtin_amdgcn_s_waitcnt(3957);       // vmcnt(5): tile nt's 5 complete
        __builtin_amdgcn_sched_barrier(0);
        TILE(nt, 0);
        if (nt + 2 < NT_COUNT) {
            STAGE(nt + 2, 0);
            __builtin_amdgcn_s_waitcnt(3957);   // vmcnt(5): tile nt+1's 5 complete
        } else {
            __builtin_amdgcn_s_waitcnt(3952);   // vmcnt(0)
        }
        __builtin_amdgcn_sched_barrier(0);
        TILE(nt + 1, 4352);
    }
#undef STAGE
#undef TILE

    // ---- per-row top-4 merge via LDS dump (4 phases of 16 rows; dump reuses stage area)
    u64* dmp = (u64*)lds;
    for (int ph = 0; ph < 4; ++ph) {
        __syncthreads();
        // every lane dumps its sorted top-4 for its 4 (ph, r) slots
#pragma unroll
        for (int r = 0; r < 4; ++r) {
            float pp[4] = {p1[ph][r], p2[ph][r], p3[ph][r], p4[ph][r]};
            u64* base = dmp + (quad * 4 + r) * 64 + n16 * 4;
#pragma unroll
            for (int j = 0; j < 4; ++j) {
                unsigned u = __float_as_uint(pp[j]);
                int k = (int)(63u - (u & 63u)) * 16 + n16;
                base[j] = ((u64)(u & ~63u) << 32) | (unsigned)(1023 - k);
            }
        }
        __syncthreads();
        if (lane < 16) {   // scan this phase's 16 rows, 64 candidates each
            const u64* c = dmp + lane * 64;
            u64 q1 = 0, q2 = 0, q3 = 0, q4 = 0;
#pragma unroll 8
            for (int i = 0; i < 64; ++i) {
                u64 v = c[i];
                u64 t1 = v > q1 ? v : q1, b1 = v > q1 ? q1 : v;
                u64 t2 = b1 > q2 ? b1 : q2, b2 = b1 > q2 ? q2 : b1;
                u64 t3 = b2 > q3 ? b2 : q3, b3 = b2 > q3 ? q3 : b2;
                q4 = b3 > q4 ? b3 : q4; q1 = t1; q2 = t2; q3 = t3;
            }
            const int row = ph * 16 + lane;
            const float v1 = __uint_as_float((unsigned)(q1 >> 32));
            const float v2 = __uint_as_float((unsigned)(q2 >> 32));
            const float v3 = __uint_as_float((unsigned)(q3 >> 32));
            const float v4 = __uint_as_float((unsigned)(q4 >> 32));
            const float xn = sqrtf(s_xn[row]) * 1.0001f;
            const float TRIG = 2.0f * (xn * Ecoef + 0.008f) + 1e-4f;
            int dep = (v1 - v2 >= TRIG) ? 1 :
                      (v2 - v3 >= TRIG) ? 2 :
                      (v3 - v4 >= TRIG) ? 3 : 0;
            s_cand[row * 4 + 0] = 1023 - (int)(q1 & 1023u);
            s_cand[row * 4 + 1] = 1023 - (int)(q2 & 1023u);
            s_cand[row * 4 + 2] = 1023 - (int)(q3 & 1023u);
            s_cand[row * 4 + 3] = 1023 - (int)(q4 & 1023u);
            s_dep[row] = dep;
            if (dep == 0) { int idx = atomicAdd(s_nfs, 1); s_fsl[idx] = row; }
        }
    }
    __syncthreads();

    // ---- fp64 rescore of top-depth candidates (certified sufficient when depth>0)
    {
        const int dep = s_dep[lane];
        int win = s_cand[lane * 4];
        if (dep >= 2) {
            const float4* __restrict__ xr = (const float4*)(X + (size_t)(wrow0 + lane) * DD);
            double bestd = 1.0e300; int bestk = 0x7fffffff;
            for (int j = 0; j < 3; ++j) {
                if (j >= dep) break;
                const int k = s_cand[lane * 4 + j];
                const float4* __restrict__ ep = (const float4*)(ET + (size_t)k * DD);
                double dot = 0.0, ee = 0.0;
#pragma unroll 4
                for (int d4 = 0; d4 < DD / 4; ++d4) {
                    const float4 xv = xr[d4];
                    const float4 evv = ep[d4];
                    const float xs[4] = {xv.x, xv.y, xv.z, xv.w};
                    const float es[4] = {evv.x, evv.y, evv.z, evv.w};
#pragma unroll
                    for (int jj = 0; jj < 4; ++jj) {
                        const double xd = (double)xs[jj];
                        const double ed = (double)es[jj];
                        dot = fma(xd, ed, dot);
                        ee  = fma(ed, ed, ee);
                    }
                }
                const double dd = ee - 2.0 * dot;
                if (dd < bestd || (dd == bestd && k < bestk)) { bestd = dd; bestk = k; }
            }
            win = bestk;
        }
        if (dep != 0) s_win[lane] = win;
    }
    __syncthreads();

    // ---- full fp64 scan for uncertifiable rows (rare; wave-cooperative, exact)
    {
        const int n = *s_nfs;
        for (int i = 0; i < n; ++i) {
            const int row = s_fsl[i];
            const float4* __restrict__ xr = (const float4*)(X + (size_t)(wrow0 + row) * DD);
            double bestd = 1.0e300; int bestk = 0x7fffffff;
            for (int c = 0; c < 16; ++c) {
                const int k = c * 64 + lane;
                const float4* __restrict__ ep = (const float4*)(ET + (size_t)k * DD);
                double dot = 0.0, ee = 0.0;
#pragma unroll 8
                for (int d4 = 0; d4 < DD / 4; ++d4) {
                    const float4 xv = xr[d4];
                    const float4 evv = ep[d4];
                    const float xs[4] = {xv.x, xv.y, xv.z, xv.w};
                    const float es[4] = {evv.x, evv.y, evv.z, evv.w};
#pragma unroll
                    for (int jj = 0; jj < 4; ++jj) {
                        const double xd = (double)xs[jj];
                        const double ed = (double)es[jj];
                        dot = fma(xd, ed, dot);
                        ee  = fma(ed, ed, ee);
                    }
                }
                const double dd = ee - 2.0 * dot;
                if (dd < bestd || (dd == bestd && k < bestk)) { bestd = dd; bestk = k; }
            }
#pragma unroll
            for (int m = 1; m < 64; m <<= 1) {
                const double od = __shfl_xor(bestd, m, 64);
                const int    ok = __shfl_xor(bestk, m, 64);
                if (od < bestd || (od == bestd && ok < bestk)) { bestd = od; bestk = ok; }
            }
            if (lane == 0) s_win[row] = bestk;
        }
    }
    __syncthreads();

    // ---- gather winning code rows (exact fp32 copies), coalesced float4
    for (int i = lane; i < RPB * (DD / 4); i += 64) {
        const int row = i >> 5;
        const int d4  = i & 31;
        const float4 v = *(const float4*)(ET + (size_t)s_win[row] * DD + d4 * 4);
        *(float4*)(Out + (size_t)(wrow0 + row) * DD + d4 * 4) = v;
    }
}

extern "C" void kernel_launch(void* const* d_in, const int* in_sizes, int n_in,
                              void* d_out, int out_size, void* d_ws, size_t ws_size,
                              hipStream_t stream) {
    const float* X = (const float*)d_in[0];   // [131072, 128]
    const float* E = (const float*)d_in[1];   // [128, 1024]
    float* Out = (float*)d_out;

    // workspace: e2h (4KB) | gtab (512B) | ET (512KB) | Bpk hi-only (256KB)
    float* e2h  = (float*)d_ws;
    float* gtab = e2h + KC;
    float* ET   = gtab + 128;
    unsigned short* Bpk = (unsigned short*)(ET + (size_t)KC * DD);

    const int N = in_sizes[0] / DD;   // 131072

    hipLaunchKernelGGL(vq_prep, dim3(NT_COUNT), dim3(256), 0, stream, E, e2h, gtab, ET, Bpk);
    hipLaunchKernelGGL(vq_main, dim3(N / RPB), dim3(64), 0, stream,
                       X, e2h, gtab, ET, Bpk, Out);
}

// Round 10
// 547.901 us; speedup vs baseline: 1.0432x; 1.0432x over previous
//
#include <hip/hip_runtime.h>

#define KC 1024   // codes
#define DD 128    // dim
#define NT_COUNT (KC / 16)   // 64 code-tiles of 16
#define RPB 64    // rows per block (one wave, 4 m-tiles)

typedef short bf16x8 __attribute__((ext_vector_type(8)));
typedef float f32x4  __attribute__((ext_vector_type(4)));
typedef unsigned long long u64;

#define AS1 __attribute__((address_space(1)))
#define AS3 __attribute__((address_space(3)))

static __device__ __forceinline__ unsigned short f2bf(float f) {
    unsigned u = __float_as_uint(f);
    unsigned r = (u + 0x7fffu + ((u >> 16) & 1u)) >> 16;   // RNE
    return (unsigned short)r;
}
static __device__ __forceinline__ float bf2f(unsigned short h) {
    return __uint_as_float(((unsigned)h) << 16);
}
static __device__ __forceinline__ void gl_lds16(const void* g, void* l) {
    __builtin_amdgcn_global_load_lds((const AS1 void*)g, (AS3 void*)l, 16, 0, 0);
}
static __device__ __forceinline__ void gl_lds4(const void* g, void* l) {
    __builtin_amdgcn_global_load_lds((const AS1 void*)g, (AS3 void*)l, 4, 0, 0);
}

// ---------------- fused prep ----------------
// e2h = 512 - 0.5||e_k||^2 ; ET = E^T (fp32 exact) ; Bpk = bf16 HI-ONLY B-frags
//   Bpk byte layout: [nt][c(4)x1024][lane(64)x16]; element (d,k):
//   d = c*32 + (lane>>4)*8 + j ; k = nt*16 + (lane&15)
// gtab[nt] = max_k ||e_k - bf16(e_k)||^2 ; gtab[64+nt] = max_k ||e_k||^2
__global__ __launch_bounds__(256) void vq_prep(const float* __restrict__ E,
                                               float* __restrict__ e2h,
                                               float* __restrict__ gtab,
                                               float* __restrict__ ET,
                                               unsigned short* __restrict__ Bpk) {
    __shared__ float T[16 * 129];   // [k][d]
    __shared__ float red[32];
    const int nt  = blockIdx.x;     // 64 blocks, 16 codes each
    const int tid = threadIdx.x;

    for (int i = tid; i < 16 * DD; i += 256) {
        int d  = i >> 4;
        int kk = i & 15;
        T[kk * 129 + d] = E[(size_t)d * KC + nt * 16 + kk];
    }
    __syncthreads();

    if (tid < 16) {
        float s = 0.f, g = 0.f;
#pragma unroll 16
        for (int d = 0; d < DD; ++d) {
            float v = T[tid * 129 + d];
            s = fmaf(v, v, s);
            float lo = v - bf2f(f2bf(v));
            g = fmaf(lo, lo, g);
        }
        e2h[nt * 16 + tid] = 512.0f - 0.5f * s;
        red[tid] = g;
        red[16 + tid] = s;
    }
    __syncthreads();
    if (tid == 0) {
        float mg = 0.f, ms = 0.f;
#pragma unroll
        for (int i = 0; i < 16; ++i) { mg = fmaxf(mg, red[i]); ms = fmaxf(ms, red[16 + i]); }
        gtab[nt] = mg;
        gtab[64 + nt] = ms;
    }

    for (int i = tid; i < 16 * DD; i += 256) {
        int kk = i >> 7;
        int d  = i & 127;
        ET[(size_t)(nt * 16 + kk) * DD + d] = T[kk * 129 + d];
    }

    {   // hi-only pack: 4 chunks x 64 lanes = 256 threads
        const int c    = tid >> 6;
        const int lane = tid & 63;
        const int kk   = lane & 15;
        const int d0   = c * 32 + (lane >> 4) * 8;
        bf16x8 hi;
#pragma unroll
        for (int j = 0; j < 8; ++j) hi[j] = (short)f2bf(T[kk * 129 + d0 + j]);
        *(bf16x8*)((char*)Bpk + (size_t)nt * 4096 + c * 1024 + lane * 16) = hi;
    }
}

// ---------------- main: R4 skeleton, 2-pass screen (B = hi limb), top-3 + certified gate ----------------
// Screen = (x_hi + x_lo)·bf16(E) + e2h. Missing x·e_lo bounded per row:
//   E_row = ||x||*(max||e_lo|| + 2^-17*max||e||) + 0.012 (mask/accum/e2h consts).
// gap12 > 2E -> k1 exact; gap13 > 2E -> fp64 top-2; else wave fp64 full scan (rare).
__global__ __launch_bounds__(64, 2) void vq_main(const float* __restrict__ X,
                                                 const float* __restrict__ e2h,
                                                 const float* __restrict__ gtab,
                                                 const float* __restrict__ ET,
                                                 const unsigned short* __restrict__ Bpk,
                                                 float* __restrict__ Out) {
    __shared__ __align__(16) char lds[11008];
    // [0, 8704): two stage buffers of 4352 ([4x1024 hi-frags][e2 256B])
    float* s_xn  = (float*)(lds + 8704);    // [64] ||x_row||^2
    int*   s_k1  = (int*)(lds + 8960);      // [64]
    int*   s_k2  = (int*)(lds + 9216);      // [64]
    int*   s_k3  = (int*)(lds + 9472);      // [64]
    float* s_g12 = (float*)(lds + 9728);    // [64]
    float* s_g13 = (float*)(lds + 9984);    // [64]
    int*   s_win = (int*)(lds + 10240);     // [64]
    int*   s_nfs = (int*)(lds + 10496);
    int*   s_fsl = (int*)(lds + 10500);     // [64]

    const int lane  = threadIdx.x;   // single wave
    const int quad  = lane >> 4;
    const int n16   = lane & 15;
    const int wrow0 = blockIdx.x * RPB;
    const int lidx16 = lane * 16;
    const int lidx4  = lane * 4;

    // ---- error-bound coefficient from prep tables (wave-wide max reduce)
    float g1 = gtab[lane];        // max ||e_lo||^2 per tile
    float g2 = gtab[64 + lane];   // max ||e||^2 per tile
#pragma unroll
    for (int m = 1; m < 64; m <<= 1) {
        g1 = fmaxf(g1, __shfl_xor(g1, m, 64));
        g2 = fmaxf(g2, __shfl_xor(g2, m, 64));
    }
    const float Ecoef = sqrtf(g1) * 1.001f + 8.0e-6f * sqrtf(g2);

    // ---- A-fragments (hi+lo limbs, 128 VGPRs) + row-norm partials
    bf16x8 ahi[4][4], alo[4][4];
    float psum[4] = {0.f, 0.f, 0.f, 0.f};
#pragma unroll
    for (int t = 0; t < 4; ++t) {
#pragma unroll
        for (int s = 0; s < 4; ++s) {
            const int row = wrow0 + t * 16 + n16;
            const int d0  = s * 32 + quad * 8;
            const float4 p = *(const float4*)(X + (size_t)row * DD + d0);
            const float4 q = *(const float4*)(X + (size_t)row * DD + d0 + 4);
            float v[8] = {p.x, p.y, p.z, p.w, q.x, q.y, q.z, q.w};
#pragma unroll
            for (int j = 0; j < 8; ++j) {
                psum[t] = fmaf(v[j], v[j], psum[t]);
                unsigned short h = f2bf(v[j]);
                ahi[t][s][j] = (short)h;
                alo[t][s][j] = (short)f2bf(v[j] - bf2f(h));
            }
        }
    }
#pragma unroll
    for (int t = 0; t < 4; ++t) {   // quad-halves reduce: full ||x_row||^2
        psum[t] += __shfl_xor(psum[t], 16, 64);
        psum[t] += __shfl_xor(psum[t], 32, 64);
    }
    if (quad == 0)
#pragma unroll
        for (int t = 0; t < 4; ++t) s_xn[t * 16 + n16] = psum[t];
    if (lane == 0) *s_nfs = 0;

    // ---- top-3 trackers: positive floats with 6-bit tile id in low mantissa bits
    float p1[4][4], p2[4][4], p3[4][4];
#pragma unroll
    for (int t = 0; t < 4; ++t)
#pragma unroll
        for (int r = 0; r < 4; ++r) { p1[t][r] = 0.f; p2[t][r] = 0.f; p3[t][r] = 0.f; }

#define STAGE(NT, BOFF)                                                          \
    do {                                                                         \
        const char* g = (const char*)Bpk + (size_t)(NT) * 4096;                  \
        _Pragma("unroll")                                                        \
        for (int c = 0; c < 4; ++c)                                              \
            gl_lds16(g + c * 1024 + lidx16, lds + (BOFF) + c * 1024);            \
        gl_lds4(e2h + (NT) * 16 + n16, lds + (BOFF) + 4096);                     \
    } while (0)

#define TILE(NT, BOFF)                                                           \
    do {                                                                         \
        const char* l = lds + (BOFF);                                            \
        const bf16x8 bh0 = *(const bf16x8*)(l + 0 * 1024 + lidx16);              \
        const bf16x8 bh1 = *(const bf16x8*)(l + 1 * 1024 + lidx16);              \
        const bf16x8 bh2 = *(const bf16x8*)(l + 2 * 1024 + lidx16);              \
        const bf16x8 bh3 = *(const bf16x8*)(l + 3 * 1024 + lidx16);              \
        const float  ev  = *(const float*)(l + 4096 + lidx4);                    \
        const unsigned ntinv = (unsigned)(63 - (NT));                            \
        _Pragma("unroll")                                                        \
        for (int t = 0; t < 4; ++t) {                                            \
            f32x4 aA = {ev, ev, ev, ev};                                         \
            f32x4 aB = {0.f, 0.f, 0.f, 0.f};                                     \
            aA = __builtin_amdgcn_mfma_f32_16x16x32_bf16(ahi[t][0], bh0, aA, 0, 0, 0); \
            aB = __builtin_amdgcn_mfma_f32_16x16x32_bf16(alo[t][0], bh0, aB, 0, 0, 0); \
            aA = __builtin_amdgcn_mfma_f32_16x16x32_bf16(ahi[t][1], bh1, aA, 0, 0, 0); \
            aB = __builtin_amdgcn_mfma_f32_16x16x32_bf16(alo[t][1], bh1, aB, 0, 0, 0); \
            aA = __builtin_amdgcn_mfma_f32_16x16x32_bf16(ahi[t][2], bh2, aA, 0, 0, 0); \
            aB = __builtin_amdgcn_mfma_f32_16x16x32_bf16(alo[t][2], bh2, aB, 0, 0, 0); \
            aA = __builtin_amdgcn_mfma_f32_16x16x32_bf16(ahi[t][3], bh3, aA, 0, 0, 0); \
            aB = __builtin_amdgcn_mfma_f32_16x16x32_bf16(alo[t][3], bh3, aB, 0, 0, 0); \
            _Pragma("unroll")                                                    \
            for (int r = 0; r < 4; ++r) {                                        \
                float sv = aA[r] + aB[r];                                        \
                float v  = __uint_as_float((__float_as_uint(sv) & ~63u) | ntinv); \
                float t1 = fmaxf(p1[t][r], v), b1 = fminf(p1[t][r], v);          \
                float t2 = fmaxf(p2[t][r], b1), b2 = fminf(p2[t][r], b1);        \
                p3[t][r] = fmaxf(p3[t][r], b2);                                  \
                p1[t][r] = t1; p2[t][r] = t2;                                    \
            }                                                                    \
        }                                                                        \
    } while (0)

    STAGE(0, 0);
    for (int nt = 0; nt < NT_COUNT; nt += 2) {
        STAGE(nt + 1, 4352);
        __builtin_amdgcn_s_waitcnt(3957);       // vmcnt(5): tile nt's 5 complete
        __builtin_amdgcn_sched_barrier(0);
        TILE(nt, 0);
        if (nt + 2 < NT_COUNT) {
            STAGE(nt + 2, 0);
            __builtin_amdgcn_s_waitcnt(3957);   // vmcnt(5): tile nt+1's 5 complete
        } else {
            __builtin_amdgcn_s_waitcnt(3952);   // vmcnt(0)
        }
        __builtin_amdgcn_sched_barrier(0);
        TILE(nt + 1, 4352);
    }
#undef STAGE
#undef TILE

    // ---- re-attach full k, merge top-3 across the 16 n-lanes (u64 butterfly, in-register)
#pragma unroll
    for (int t = 0; t < 4; ++t) {
#pragma unroll
        for (int r = 0; r < 4; ++r) {
            unsigned u1 = __float_as_uint(p1[t][r]);
            unsigned u2 = __float_as_uint(p2[t][r]);
            unsigned u3 = __float_as_uint(p3[t][r]);
            int k1 = (int)(63u - (u1 & 63u)) * 16 + n16;
            int k2 = (int)(63u - (u2 & 63u)) * 16 + n16;
            int k3 = (int)(63u - (u3 & 63u)) * 16 + n16;
            u64 q1 = ((u64)(u1 & ~63u) << 32) | (unsigned)(1023 - k1);
            u64 q2 = ((u64)(u2 & ~63u) << 32) | (unsigned)(1023 - k2);
            u64 q3 = ((u64)(u3 & ~63u) << 32) | (unsigned)(1023 - k3);
#pragma unroll
            for (int m = 1; m < 16; m <<= 1) {
                u64 o1 = __shfl_xor(q1, m, 64);
                u64 o2 = __shfl_xor(q2, m, 64);
                u64 o3 = __shfl_xor(q3, m, 64);
                u64 n1 = q1 > o1 ? q1 : o1;
                u64 m1 = q1 > o1 ? o1 : q1;
                u64 h2 = q2 > o2 ? q2 : o2;
                u64 n2 = m1 > h2 ? m1 : h2;
                u64 l2 = m1 > h2 ? h2 : m1;
                u64 h3 = q3 > o3 ? q3 : o3;
                u64 n3 = l2 > h3 ? l2 : h3;
                q1 = n1; q2 = n2; q3 = n3;
            }
            if (n16 == 0) {
                int row = t * 16 + quad * 4 + r;
                s_k1[row] = 1023 - (int)(q1 & 1023u);
                s_k2[row] = 1023 - (int)(q2 & 1023u);
                s_k3[row] = 1023 - (int)(q3 & 1023u);
                const float v1 = __uint_as_float((unsigned)(q1 >> 32));
                const float v2 = __uint_as_float((unsigned)(q2 >> 32));
                const float v3 = __uint_as_float((unsigned)(q3 >> 32));
                s_g12[row] = v1 - v2;
                s_g13[row] = v1 - v3;
            }
        }
    }
    __syncthreads();

    // ---- per-row certified decision + fp64 top-2 rescore
    {
        const float xn   = sqrtf(s_xn[lane]) * 1.0001f;
        const float TRIG = 2.0f * (xn * Ecoef + 0.012f) + 2e-3f;
        const int k1 = s_k1[lane];
        const int k2 = s_k2[lane];
        int win = k1;
        bool fullscan = false;
        if (s_g12[lane] < TRIG) {
            if (s_g13[lane] < TRIG) {
                fullscan = true;   // can't certify k* in top-3's reach; brute force
            } else {
                // k* certified within {k1, k2}: fp64 rescore both
                const float4* __restrict__ xr = (const float4*)(X + (size_t)(wrow0 + lane) * DD);
                const float4* __restrict__ e1 = (const float4*)(ET + (size_t)k1 * DD);
                const float4* __restrict__ e2p = (const float4*)(ET + (size_t)k2 * DD);
                double dot1 = 0.0, ee1 = 0.0, dot2 = 0.0, ee2 = 0.0;
#pragma unroll 4
                for (int d4 = 0; d4 < DD / 4; ++d4) {
                    const float4 xv = xr[d4];
                    const float4 v1 = e1[d4];
                    const float4 v2 = e2p[d4];
                    const float xs[4] = {xv.x, xv.y, xv.z, xv.w};
                    const float a1[4] = {v1.x, v1.y, v1.z, v1.w};
                    const float a2[4] = {v2.x, v2.y, v2.z, v2.w};
#pragma unroll
                    for (int j = 0; j < 4; ++j) {
                        const double xd  = (double)xs[j];
                        const double v1d = (double)a1[j];
                        const double v2d = (double)a2[j];
                        dot1 = fma(xd, v1d, dot1);
                        ee1  = fma(v1d, v1d, ee1);
                        dot2 = fma(xd, v2d, dot2);
                        ee2  = fma(v2d, v2d, ee2);
                    }
                }
                double d1 = ee1 - 2.0 * dot1;
                double d2 = ee2 - 2.0 * dot2;
                win = (d2 < d1 || (d2 == d1 && k2 < k1)) ? k2 : k1;
            }
        }
        if (fullscan) { int idx = atomicAdd(s_nfs, 1); s_fsl[idx] = lane; }
        else s_win[lane] = win;
    }
    __syncthreads();

    // ---- full fp64 scan for uncertifiable rows (rare; wave-cooperative, exact)
    {
        const int n = *s_nfs;
        for (int i = 0; i < n; ++i) {
            const int row = s_fsl[i];
            const float4* __restrict__ xr = (const float4*)(X + (size_t)(wrow0 + row) * DD);
            double bestd = 1.0e300; int bestk = 0x7fffffff;
            for (int c = 0; c < 16; ++c) {
                const int k = c * 64 + lane;
                const float4* __restrict__ ep = (const float4*)(ET + (size_t)k * DD);
                double dot = 0.0, ee = 0.0;
#pragma unroll 8
                for (int d4 = 0; d4 < DD / 4; ++d4) {
                    const float4 xv = xr[d4];
                    const float4 evv = ep[d4];
                    const float xs[4] = {xv.x, xv.y, xv.z, xv.w};
                    const float es[4] = {evv.x, evv.y, evv.z, evv.w};
#pragma unroll
                    for (int jj = 0; jj < 4; ++jj) {
                        const double xd = (double)xs[jj];
                        const double ed = (double)es[jj];
                        dot = fma(xd, ed, dot);
                        ee  = fma(ed, ed, ee);
                    }
                }
                const double dd = ee - 2.0 * dot;
                if (dd < bestd || (dd == bestd && k < bestk)) { bestd = dd; bestk = k; }
            }
#pragma unroll
            for (int m = 1; m < 64; m <<= 1) {
                const double od = __shfl_xor(bestd, m, 64);
                const int    ok = __shfl_xor(bestk, m, 64);
                if (od < bestd || (od == bestd && ok < bestk)) { bestd = od; bestk = ok; }
            }
            if (lane == 0) s_win[row] = bestk;
        }
    }
    __syncthreads();

    // ---- gather winning code rows (exact fp32 copies), coalesced float4
    for (int i = lane; i < RPB * (DD / 4); i += 64) {
        const int row = i >> 5;
        const int d4  = i & 31;
        const float4 v = *(const float4*)(ET + (size_t)s_win[row] * DD + d4 * 4);
        *(float4*)(Out + (size_t)(wrow0 + row) * DD + d4 * 4) = v;
    }
}

extern "C" void kernel_launch(void* const* d_in, const int* in_sizes, int n_in,
                              void* d_out, int out_size, void* d_ws, size_t ws_size,
                              hipStream_t stream) {
    const float* X = (const float*)d_in[0];   // [131072, 128]
    const float* E = (const float*)d_in[1];   // [128, 1024]
    float* Out = (float*)d_out;

    // workspace: e2h (4KB) | gtab (512B) | ET (512KB) | Bpk hi-only (256KB)
    float* e2h  = (float*)d_ws;
    float* gtab = e2h + KC;
    float* ET   = gtab + 128;
    unsigned short* Bpk = (unsigned short*)(ET + (size_t)KC * DD);

    const int N = in_sizes[0] / DD;   // 131072

    hipLaunchKernelGGL(vq_prep, dim3(NT_COUNT), dim3(256), 0, stream, E, e2h, gtab, ET, Bpk);
    hipLaunchKernelGGL(vq_main, dim3(N / RPB), dim3(64), 0, stream,
                       X, e2h, gtab, ET, Bpk, Out);
}